// Round 3
// baseline (406.372 us; speedup 1.0000x reference)
//
#include <hip/hip_runtime.h>
#include <math.h>

#define N_NODES 50000
#define IN_DIM 256
#define HEADS 4
#define CDIM 64
#define HC 256        // HEADS*CDIM
#define HOPS 3
#define EDGES 400000
#define NEG_SLOPE 0.2f
#define SEG (EDGES + N_NODES)            // hop0 flat range incl self-loops
#define TOT_E (3 * EDGES + N_NODES)      // flat edge count across hops
#define CAP 40                           // bucket capacity; P(Poisson(8)+1 > 40) ~ 1e-16

// prep kernel block ranges
#define NB_GATE  ((N_NODES + 3) / 4)             // 12500
#define NB_PACKW ((IN_DIM * 2 * HC) / 256)       // 512
#define NB_SCAT  ((TOT_E + 255) / 256)           // 4883
// gemm grid
#define GEMM_BX  ((N_NODES + 127) / 128)         // 391

typedef unsigned short ushort;
using short8  = __attribute__((ext_vector_type(8))) short;
using floatx4 = __attribute__((ext_vector_type(4))) float;
using f32x2   = __attribute__((ext_vector_type(2))) float;

// flat layout: hop0 [0, E+N) incl self-loops ; hop1 [SEG, SEG+E) ; hop2 [...]
__device__ __forceinline__ void decode_flat(int f, int& k, int& e)
{
    if (f < SEG)              { k = 0; e = f; }
    else if (f < SEG + EDGES) { k = 1; e = f - SEG; }
    else                      { k = 2; e = f - SEG - EDGES; }
}

__device__ __forceinline__ ushort f2bf(float f)
{
    unsigned u = __float_as_uint(f);
    unsigned r = u + 0x7fffu + ((u >> 16) & 1u);   // RNE
    return (ushort)(r >> 16);
}

// unpack 2 bf16 (packed in a uint) -> f32x2 {lo, hi}
__device__ __forceinline__ f32x2 bf2x(unsigned u)
{
    f32x2 r;
    r.x = __uint_as_float(u << 16);
    r.y = __uint_as_float(u & 0xffff0000u);
    return r;
}

// leaky-relu slope 0.2: max(v, 0.2v)  -> v_pk_mul_f32 + v_pk_max_f32
__device__ __forceinline__ f32x2 lrelu2(f32x2 v)
{
    return __builtin_elementwise_max(v, 0.2f * v);
}

// ---------------------------------------------------------------------------
// prep: fused [gate+pack_x | pack_w | direct bucket scatter] by blockIdx range.
// (unchanged from baseline)
// ---------------------------------------------------------------------------
__global__ __launch_bounds__(256) void prep(
    const float* __restrict__ X, const float* __restrict__ Wg,
    const float* __restrict__ bg, float* __restrict__ gw,
    ushort* __restrict__ Xb,
    const float* __restrict__ Wl, const float* __restrict__ Wr,
    ushort* __restrict__ WT,
    const int* __restrict__ ei0, const int* __restrict__ ei1,
    const int* __restrict__ ei2, int* __restrict__ cnt,
    int* __restrict__ bucket)
{
    const int blk = blockIdx.x;
    const int tid = threadIdx.x;

    if (blk < NB_GATE) {
        // ---- gate + bf16 pack of x: one wave per node ----
        const int node = (blk * 256 + tid) >> 6;
        const int lane = tid & 63;
        if (node >= N_NODES) return;

        float4 xv = ((const float4*)(X + (size_t)node * IN_DIM))[lane];

        union { ushort s[4]; uint2 u; } o;
        o.s[0] = f2bf(xv.x); o.s[1] = f2bf(xv.y);
        o.s[2] = f2bf(xv.z); o.s[3] = f2bf(xv.w);
        ((uint2*)(Xb + (size_t)node * IN_DIM))[lane] = o.u;

        float a0 = 0.f, a1 = 0.f, a2 = 0.f;
        const int i0 = lane * 4;
        a0 += xv.x * Wg[(i0 + 0) * HOPS + 0]; a1 += xv.x * Wg[(i0 + 0) * HOPS + 1]; a2 += xv.x * Wg[(i0 + 0) * HOPS + 2];
        a0 += xv.y * Wg[(i0 + 1) * HOPS + 0]; a1 += xv.y * Wg[(i0 + 1) * HOPS + 1]; a2 += xv.y * Wg[(i0 + 1) * HOPS + 2];
        a0 += xv.z * Wg[(i0 + 2) * HOPS + 0]; a1 += xv.z * Wg[(i0 + 2) * HOPS + 1]; a2 += xv.z * Wg[(i0 + 2) * HOPS + 2];
        a0 += xv.w * Wg[(i0 + 3) * HOPS + 0]; a1 += xv.w * Wg[(i0 + 3) * HOPS + 1]; a2 += xv.w * Wg[(i0 + 3) * HOPS + 2];

        #pragma unroll
        for (int off = 32; off >= 1; off >>= 1) {
            a0 += __shfl_xor(a0, off);
            a1 += __shfl_xor(a1, off);
            a2 += __shfl_xor(a2, off);
        }
        if (lane == 0) {
            float l0 = a0 + bg[0], l1 = a1 + bg[1], l2 = a2 + bg[2];
            float m = fmaxf(l0, fmaxf(l1, l2));
            float e0 = expf(l0 - m), e1 = expf(l1 - m), e2 = expf(l2 - m);
            float inv = 1.f / (e0 + e1 + e2);
            gw[node * HOPS + 0] = e0 * inv;
            gw[node * HOPS + 1] = e1 * inv;
            gw[node * HOPS + 2] = e2 * inv;
        }
    } else if (blk < NB_GATE + NB_PACKW) {
        // ---- pack W: WT[n][k]; coalesced writes, gather reads (W L2-resident)
        int id = (blk - NB_GATE) * 256 + tid;
        int n = id >> 8;            // 0..511
        int k = id & 255;           // 0..255
        float v = (n < HC) ? Wl[k * HC + n] : Wr[k * HC + (n - HC)];
        WT[(size_t)n * IN_DIM + k] = f2bf(v);
    } else {
        // ---- direct bucket scatter ----
        int f = (blk - NB_GATE - NB_PACKW) * 256 + tid;
        if (f >= TOT_E) return;
        int k, e; decode_flat(f, k, e);
        int s, d;
        if (k == 0 && e >= EDGES) { s = d = e - EDGES; }
        else {
            const int* ei = (k == 0) ? ei0 : (k == 1) ? ei1 : ei2;
            s = ei[e]; d = ei[EDGES + e];
        }
        int pos = atomicAdd(&cnt[k * N_NODES + d], 1);
        if (pos < CAP)
            bucket[((size_t)k * N_NODES + d) * CAP + pos] = s;
    }
}

// ---------------------------------------------------------------------------
// bf16 MFMA GEMM with swapped operands (wide stores): xlb | xrb both bf16.
// (unchanged from baseline)
// ---------------------------------------------------------------------------
#define TM 128
#define TN 128
#define TK 32
#define LDP 40

__global__ __launch_bounds__(256) void gemm_mfma(
    const ushort* __restrict__ Xb, const ushort* __restrict__ WT,
    const float* __restrict__ b_l, const float* __restrict__ b_r,
    ushort* __restrict__ xlb, ushort* __restrict__ xrb, int M)
{
    __shared__ ushort As[TM][LDP];
    __shared__ ushort Bs[TN][LDP];
    const int tid  = threadIdx.x;
    const int wave = tid >> 6, lane = tid & 63;
    const int row0 = blockIdx.x * TM;
    const int col0 = blockIdx.y * TN;
    const int wy = (wave >> 1) * 64, wx = (wave & 1) * 64;
    const int lrow = lane & 15, lk = (lane >> 4) * 8;

    floatx4 acc[4][4];
    #pragma unroll
    for (int i = 0; i < 4; i++)
        #pragma unroll
        for (int j = 0; j < 4; j++)
            acc[i][j] = (floatx4){0.f, 0.f, 0.f, 0.f};

    for (int k0 = 0; k0 < IN_DIM; k0 += TK) {
        #pragma unroll
        for (int j = 0; j < 2; j++) {
            int id = tid + 256 * j;
            int r  = id >> 2;
            int c  = (id & 3) * 8;
            int gr = row0 + r;
            uint4 v = make_uint4(0u, 0u, 0u, 0u);
            if (gr < M)
                v = *(const uint4*)(Xb + (size_t)gr * IN_DIM + k0 + c);
            *(uint4*)&As[r][c] = v;
        }
        #pragma unroll
        for (int j = 0; j < 2; j++) {
            int id = tid + 256 * j;
            int r  = id >> 2;
            int c  = (id & 3) * 8;
            *(uint4*)&Bs[r][c] =
                *(const uint4*)(WT + (size_t)(col0 + r) * IN_DIM + k0 + c);
        }
        __syncthreads();

        short8 af[4], bf[4];
        #pragma unroll
        for (int mi = 0; mi < 4; mi++)
            af[mi] = *(const short8*)&As[wy + mi * 16 + lrow][lk];
        #pragma unroll
        for (int ni = 0; ni < 4; ni++)
            bf[ni] = *(const short8*)&Bs[wx + ni * 16 + lrow][lk];

        #pragma unroll
        for (int mi = 0; mi < 4; mi++)
            #pragma unroll
            for (int ni = 0; ni < 4; ni++)
                acc[mi][ni] = __builtin_amdgcn_mfma_f32_16x16x32_bf16(
                    bf[ni], af[mi], acc[mi][ni], 0, 0, 0);
        __syncthreads();
    }

    const int csub = (lane >> 4) * 4;
    #pragma unroll
    for (int mi = 0; mi < 4; mi++) {
        int grow = row0 + wy + mi * 16 + lrow;
        if (grow < M) {
            #pragma unroll
            for (int ni = 0; ni < 4; ni++) {
                int gcol = col0 + wx + ni * 16 + csub;
                floatx4 v = acc[mi][ni];
                const bool left = (gcol < HC);
                const float4 b = left ? *(const float4*)(b_l + gcol)
                                      : *(const float4*)(b_r + gcol - HC);
                union { ushort s[4]; uint2 u; } o;
                o.s[0] = f2bf(v[0] + b.x);
                o.s[1] = f2bf(v[1] + b.y);
                o.s[2] = f2bf(v[2] + b.z);
                o.s[3] = f2bf(v[3] + b.w);
                ushort* dst = left ? (xlb + (size_t)grow * HC + gcol)
                                   : (xrb + (size_t)grow * HC + gcol - HC);
                *(uint2*)dst = o.u;
            }
        }
    }
}

// ---------------------------------------------------------------------------
// node_all v6: ONE wave per node handles all 3 hops sequentially (4 nodes per
// 256-thread block). Per-node fixed work (xr unpack, addressing, output path)
// amortized 3x; no LDS, no __syncthreads. Inner math in packed f32 (f32x2 ->
// v_pk_add/pk_max/pk_fma); lrelu as max(v, 0.2v); 32-bit gather offsets.
// Two edges per iteration (32 lanes each, uint4 = 8 bf16 ch/lane), 1-pair
// prefetch. Reduction order per hop (v5 bug fixed): xor-32 half-merge ->
// per-head normalize by inv (denom is PER-HEAD at this point) -> xor-8/16
// head mean. gw+bias folded into per-node output acc; one 256 B store.
// ---------------------------------------------------------------------------
__global__ __launch_bounds__(256) void node_all(
    const ushort* __restrict__ xlb, const ushort* __restrict__ xrb,
    const int* __restrict__ cnt, const int* __restrict__ bucket,
    const float* __restrict__ att, const float* __restrict__ gw,
    const float* __restrict__ bias, float* __restrict__ out)
{
    const int n    = blockIdx.x * 4 + (threadIdx.x >> 6);
    const int lane = threadIdx.x & 63;
    if (n >= N_NODES) return;
    const int half = lane >> 5;          // which edge of the pair
    const int sub  = lane & 31;          // channel group: ch = sub*8 .. sub*8+7
    const unsigned laneoff = (unsigned)sub * 8;   // element offset within a row

    // xr channels for this lane (bf16 -> f32x2 pairs), shared across hops
    uint4 rq = *(const uint4*)(xrb + (size_t)n * HC + laneoff);
    f32x2 rr[4] = { bf2x(rq.x), bf2x(rq.y), bf2x(rq.z), bf2x(rq.w) };

    f32x2 outacc[4] = { {0.f,0.f}, {0.f,0.f}, {0.f,0.f}, {0.f,0.f} };

    #pragma unroll
    for (int k = 0; k < HOPS; ++k) {
        const int deg = min(cnt[k * N_NODES + n], CAP);
        const int* bk = bucket + ((size_t)k * N_NODES + n) * CAP;

        const float4 a0 = ((const float4*)(att + (size_t)k * HC))[sub * 2 + 0];
        const float4 a1 = ((const float4*)(att + (size_t)k * HC))[sub * 2 + 1];
        f32x2 w2[4] = { {a0.x, a0.y}, {a0.z, a0.w}, {a1.x, a1.y}, {a1.z, a1.w} };

        float denom = 0.f;
        f32x2 acc2[4] = { {0.f,0.f}, {0.f,0.f}, {0.f,0.f}, {0.f,0.f} };

        if (deg > 0) {
            const int degm1 = deg - 1;
            int myS = (lane < deg) ? bk[lane] : 0;
            const int npair = (deg + 1) >> 1;

            int s0 = __shfl(myS, min(half, degm1));
            uint4 q = *(const uint4*)(xlb + (unsigned)s0 * HC + laneoff);

            for (int j = 0; j < npair; j++) {
                int sn = __shfl(myS, min(2 * (j + 1) + half, degm1));
                uint4 qn = *(const uint4*)(xlb + (unsigned)sn * HC + laneoff);

                f32x2 f0 = bf2x(q.x), f1 = bf2x(q.y);
                f32x2 f2 = bf2x(q.z), f3 = bf2x(q.w);

                f32x2 pp = w2[0] * lrelu2(f0 + rr[0]);
                pp = __builtin_elementwise_fma(w2[1], lrelu2(f1 + rr[1]), pp);
                pp = __builtin_elementwise_fma(w2[2], lrelu2(f2 + rr[2]), pp);
                pp = __builtin_elementwise_fma(w2[3], lrelu2(f3 + rr[3]), pp);
                float p = pp.x + pp.y;

                // per-head reduce: head = 8 consecutive lanes (within half)
                p += __shfl_xor(p, 1);
                p += __shfl_xor(p, 2);
                p += __shfl_xor(p, 4);

                bool valid = (2 * j + half) < deg;
                float ex = valid ? __expf(p) : 0.f;
                denom += ex;
                f32x2 ex2 = { ex, ex };
                acc2[0] = __builtin_elementwise_fma(ex2, f0, acc2[0]);
                acc2[1] = __builtin_elementwise_fma(ex2, f1, acc2[1]);
                acc2[2] = __builtin_elementwise_fma(ex2, f2, acc2[2]);
                acc2[3] = __builtin_elementwise_fma(ex2, f3, acc2[3]);
                q = qn;
            }
        }

        // merge halves (xor-32): denom & acc are per-head after this.
        denom += __shfl_xor(denom, 32);
        const float inv = (denom > 0.f) ? 1.f / denom : 0.f;
        // per-head normalize FIRST (each lane still carries its own head),
        // THEN head mean across lanes {sub&7, +8, +16, +24} (xor-8, xor-16).
        #pragma unroll
        for (int i = 0; i < 4; i++) {
            acc2[i].x += __shfl_xor(acc2[i].x, 32);
            acc2[i].y += __shfl_xor(acc2[i].y, 32);
            acc2[i].x *= inv;
            acc2[i].y *= inv;
            acc2[i].x += __shfl_xor(acc2[i].x, 8);
            acc2[i].y += __shfl_xor(acc2[i].y, 8);
            acc2[i].x += __shfl_xor(acc2[i].x, 16);
            acc2[i].y += __shfl_xor(acc2[i].y, 16);
        }

        const float g   = gw[n * HOPS + k];
        const float s   = g * 0.25f;           // head mean /4 folded
        const f32x2 s2  = { s, s };
        const f32x2 g2  = { g, g };
        const f32x2* bb2 =
            (const f32x2*)(bias + (size_t)k * CDIM + (size_t)(sub & 7) * 8);
        #pragma unroll
        for (int i = 0; i < 4; i++) {
            outacc[i] = __builtin_elementwise_fma(s2, acc2[i], outacc[i]);
            outacc[i] = __builtin_elementwise_fma(g2, bb2[i], outacc[i]);
        }
    }

    if (lane < 8) {
        float4 o0 = { outacc[0].x, outacc[0].y, outacc[1].x, outacc[1].y };
        float4 o1 = { outacc[2].x, outacc[2].y, outacc[3].x, outacc[3].y };
        float4* dst = (float4*)(out + (size_t)n * CDIM + (size_t)lane * 8);
        dst[0] = o0;
        dst[1] = o1;
    }
}

// ---------------------------------------------------------------------------
extern "C" void kernel_launch(void* const* d_in, const int* in_sizes, int n_in,
                              void* d_out, int out_size, void* d_ws, size_t ws_size,
                              hipStream_t stream)
{
    const float* x      = (const float*)d_in[0];
    const int*   ei0    = (const int*)d_in[1];
    const int*   ei1    = (const int*)d_in[2];
    const int*   ei2    = (const int*)d_in[3];
    const float* W_l    = (const float*)d_in[4];
    const float* b_l    = (const float*)d_in[5];
    const float* W_r    = (const float*)d_in[6];
    const float* b_r    = (const float*)d_in[7];
    const float* att    = (const float*)d_in[8];   // [3,4,64]
    const float* bias   = (const float*)d_in[9];   // [3,64]
    const float* W_gate = (const float*)d_in[10];  // [256,3]
    const float* b_gate = (const float*)d_in[11];  // [3]

    const size_t NHC = (size_t)N_NODES * HC;       // 12,800,000
    float* ws      = (float*)d_ws;
    float* gwbuf   = ws;                           // 150,000
    int*   cnt     = (int*)(gwbuf + HOPS * N_NODES);         // 150,000
    int*   bucket  = cnt + HOPS * N_NODES;         // 3*N*CAP = 6,000,000
    ushort* xlb    = (ushort*)(bucket + (size_t)HOPS * N_NODES * CAP); // NHC bf16
    ushort* xrb    = xlb + NHC;                    // NHC bf16
    ushort* Xb     = xrb + NHC;                    // NHC bf16
    ushort* WT     = Xb + NHC;                     // 131,072 bf16

    hipMemsetAsync(cnt, 0, (size_t)HOPS * N_NODES * sizeof(int), stream);

    // fused gate+pack_x | pack_w | bucket scatter
    prep<<<NB_GATE + NB_PACKW + NB_SCAT, 256, 0, stream>>>(
        x, W_gate, b_gate, gwbuf, Xb, W_l, W_r, WT,
        ei0, ei1, ei2, cnt, bucket);

    // bf16 MFMA GEMM -> xlb | xrb (both bf16)
    dim3 ggrid(GEMM_BX, 4);
    gemm_mfma<<<ggrid, 256, 0, stream>>>(Xb, WT, b_l, b_r, xlb, xrb, N_NODES);

    // fused logits + softmax + aggregate + head-mean + gate combine
    node_all<<<(N_NODES + 3) / 4, 256, 0, stream>>>(
        xlb, xrb, cnt, bucket, att, gwbuf, bias, (float*)d_out);
}

// Round 4
// 377.578 us; speedup vs baseline: 1.0763x; 1.0763x over previous
//
#include <hip/hip_runtime.h>
#include <math.h>

#define N_NODES 50000
#define IN_DIM 256
#define HEADS 4
#define CDIM 64
#define HC 256        // HEADS*CDIM
#define HOPS 3
#define EDGES 400000
#define NEG_SLOPE 0.2f
#define SEG (EDGES + N_NODES)            // hop0 flat range incl self-loops
#define TOT_E (3 * EDGES + N_NODES)      // flat edge count across hops
#define CAP 40                           // bucket capacity; P(Poisson(8)+1 > 40) ~ 1e-16

// prep kernel block ranges
#define NB_GATE  ((N_NODES + 3) / 4)             // 12500
#define NB_PACKW ((IN_DIM * 2 * HC) / 256)       // 512
#define NB_SCAT  ((TOT_E + 255) / 256)           // 4883
// gemm grid
#define GEMM_BX  ((N_NODES + 127) / 128)         // 391

typedef unsigned short ushort;
using short8  = __attribute__((ext_vector_type(8))) short;
using floatx4 = __attribute__((ext_vector_type(4))) float;
using f32x2   = __attribute__((ext_vector_type(2))) float;

// flat layout: hop0 [0, E+N) incl self-loops ; hop1 [SEG, SEG+E) ; hop2 [...]
__device__ __forceinline__ void decode_flat(int f, int& k, int& e)
{
    if (f < SEG)              { k = 0; e = f; }
    else if (f < SEG + EDGES) { k = 1; e = f - SEG; }
    else                      { k = 2; e = f - SEG - EDGES; }
}

__device__ __forceinline__ ushort f2bf(float f)
{
    unsigned u = __float_as_uint(f);
    unsigned r = u + 0x7fffu + ((u >> 16) & 1u);   // RNE
    return (ushort)(r >> 16);
}

// unpack 2 bf16 (packed in a uint) -> f32x2 {lo, hi}
__device__ __forceinline__ f32x2 bf2x(unsigned u)
{
    f32x2 r;
    r.x = __uint_as_float(u << 16);
    r.y = __uint_as_float(u & 0xffff0000u);
    return r;
}

// leaky-relu slope 0.2: max(v, 0.2v)  -> v_pk_mul_f32 + v_pk_max_f32
__device__ __forceinline__ f32x2 lrelu2(f32x2 v)
{
    return __builtin_elementwise_max(v, 0.2f * v);
}

// ---------------------------------------------------------------------------
// prep: fused [gate+pack_x | pack_w | direct bucket scatter] by blockIdx range.
// (unchanged from baseline)
// ---------------------------------------------------------------------------
__global__ __launch_bounds__(256) void prep(
    const float* __restrict__ X, const float* __restrict__ Wg,
    const float* __restrict__ bg, float* __restrict__ gw,
    ushort* __restrict__ Xb,
    const float* __restrict__ Wl, const float* __restrict__ Wr,
    ushort* __restrict__ WT,
    const int* __restrict__ ei0, const int* __restrict__ ei1,
    const int* __restrict__ ei2, int* __restrict__ cnt,
    int* __restrict__ bucket)
{
    const int blk = blockIdx.x;
    const int tid = threadIdx.x;

    if (blk < NB_GATE) {
        // ---- gate + bf16 pack of x: one wave per node ----
        const int node = (blk * 256 + tid) >> 6;
        const int lane = tid & 63;
        if (node >= N_NODES) return;

        float4 xv = ((const float4*)(X + (size_t)node * IN_DIM))[lane];

        union { ushort s[4]; uint2 u; } o;
        o.s[0] = f2bf(xv.x); o.s[1] = f2bf(xv.y);
        o.s[2] = f2bf(xv.z); o.s[3] = f2bf(xv.w);
        ((uint2*)(Xb + (size_t)node * IN_DIM))[lane] = o.u;

        float a0 = 0.f, a1 = 0.f, a2 = 0.f;
        const int i0 = lane * 4;
        a0 += xv.x * Wg[(i0 + 0) * HOPS + 0]; a1 += xv.x * Wg[(i0 + 0) * HOPS + 1]; a2 += xv.x * Wg[(i0 + 0) * HOPS + 2];
        a0 += xv.y * Wg[(i0 + 1) * HOPS + 0]; a1 += xv.y * Wg[(i0 + 1) * HOPS + 1]; a2 += xv.y * Wg[(i0 + 1) * HOPS + 2];
        a0 += xv.z * Wg[(i0 + 2) * HOPS + 0]; a1 += xv.z * Wg[(i0 + 2) * HOPS + 1]; a2 += xv.z * Wg[(i0 + 2) * HOPS + 2];
        a0 += xv.w * Wg[(i0 + 3) * HOPS + 0]; a1 += xv.w * Wg[(i0 + 3) * HOPS + 1]; a2 += xv.w * Wg[(i0 + 3) * HOPS + 2];

        #pragma unroll
        for (int off = 32; off >= 1; off >>= 1) {
            a0 += __shfl_xor(a0, off);
            a1 += __shfl_xor(a1, off);
            a2 += __shfl_xor(a2, off);
        }
        if (lane == 0) {
            float l0 = a0 + bg[0], l1 = a1 + bg[1], l2 = a2 + bg[2];
            float m = fmaxf(l0, fmaxf(l1, l2));
            float e0 = expf(l0 - m), e1 = expf(l1 - m), e2 = expf(l2 - m);
            float inv = 1.f / (e0 + e1 + e2);
            gw[node * HOPS + 0] = e0 * inv;
            gw[node * HOPS + 1] = e1 * inv;
            gw[node * HOPS + 2] = e2 * inv;
        }
    } else if (blk < NB_GATE + NB_PACKW) {
        // ---- pack W: WT[n][k]; coalesced writes, gather reads (W L2-resident)
        int id = (blk - NB_GATE) * 256 + tid;
        int n = id >> 8;            // 0..511
        int k = id & 255;           // 0..255
        float v = (n < HC) ? Wl[k * HC + n] : Wr[k * HC + (n - HC)];
        WT[(size_t)n * IN_DIM + k] = f2bf(v);
    } else {
        // ---- direct bucket scatter ----
        int f = (blk - NB_GATE - NB_PACKW) * 256 + tid;
        if (f >= TOT_E) return;
        int k, e; decode_flat(f, k, e);
        int s, d;
        if (k == 0 && e >= EDGES) { s = d = e - EDGES; }
        else {
            const int* ei = (k == 0) ? ei0 : (k == 1) ? ei1 : ei2;
            s = ei[e]; d = ei[EDGES + e];
        }
        int pos = atomicAdd(&cnt[k * N_NODES + d], 1);
        if (pos < CAP)
            bucket[((size_t)k * N_NODES + d) * CAP + pos] = s;
    }
}

// ---------------------------------------------------------------------------
// bf16 MFMA GEMM with swapped operands (wide stores): xlb | xrb both bf16.
// (unchanged from baseline)
// ---------------------------------------------------------------------------
#define TM 128
#define TN 128
#define TK 32
#define LDP 40

__global__ __launch_bounds__(256) void gemm_mfma(
    const ushort* __restrict__ Xb, const ushort* __restrict__ WT,
    const float* __restrict__ b_l, const float* __restrict__ b_r,
    ushort* __restrict__ xlb, ushort* __restrict__ xrb, int M)
{
    __shared__ ushort As[TM][LDP];
    __shared__ ushort Bs[TN][LDP];
    const int tid  = threadIdx.x;
    const int wave = tid >> 6, lane = tid & 63;
    const int row0 = blockIdx.x * TM;
    const int col0 = blockIdx.y * TN;
    const int wy = (wave >> 1) * 64, wx = (wave & 1) * 64;
    const int lrow = lane & 15, lk = (lane >> 4) * 8;

    floatx4 acc[4][4];
    #pragma unroll
    for (int i = 0; i < 4; i++)
        #pragma unroll
        for (int j = 0; j < 4; j++)
            acc[i][j] = (floatx4){0.f, 0.f, 0.f, 0.f};

    for (int k0 = 0; k0 < IN_DIM; k0 += TK) {
        #pragma unroll
        for (int j = 0; j < 2; j++) {
            int id = tid + 256 * j;
            int r  = id >> 2;
            int c  = (id & 3) * 8;
            int gr = row0 + r;
            uint4 v = make_uint4(0u, 0u, 0u, 0u);
            if (gr < M)
                v = *(const uint4*)(Xb + (size_t)gr * IN_DIM + k0 + c);
            *(uint4*)&As[r][c] = v;
        }
        #pragma unroll
        for (int j = 0; j < 2; j++) {
            int id = tid + 256 * j;
            int r  = id >> 2;
            int c  = (id & 3) * 8;
            *(uint4*)&Bs[r][c] =
                *(const uint4*)(WT + (size_t)(col0 + r) * IN_DIM + k0 + c);
        }
        __syncthreads();

        short8 af[4], bf[4];
        #pragma unroll
        for (int mi = 0; mi < 4; mi++)
            af[mi] = *(const short8*)&As[wy + mi * 16 + lrow][lk];
        #pragma unroll
        for (int ni = 0; ni < 4; ni++)
            bf[ni] = *(const short8*)&Bs[wx + ni * 16 + lrow][lk];

        #pragma unroll
        for (int mi = 0; mi < 4; mi++)
            #pragma unroll
            for (int ni = 0; ni < 4; ni++)
                acc[mi][ni] = __builtin_amdgcn_mfma_f32_16x16x32_bf16(
                    bf[ni], af[mi], acc[mi][ni], 0, 0, 0);
        __syncthreads();
    }

    const int csub = (lane >> 4) * 4;
    #pragma unroll
    for (int mi = 0; mi < 4; mi++) {
        int grow = row0 + wy + mi * 16 + lrow;
        if (grow < M) {
            #pragma unroll
            for (int ni = 0; ni < 4; ni++) {
                int gcol = col0 + wx + ni * 16 + csub;
                floatx4 v = acc[mi][ni];
                const bool left = (gcol < HC);
                const float4 b = left ? *(const float4*)(b_l + gcol)
                                      : *(const float4*)(b_r + gcol - HC);
                union { ushort s[4]; uint2 u; } o;
                o.s[0] = f2bf(v[0] + b.x);
                o.s[1] = f2bf(v[1] + b.y);
                o.s[2] = f2bf(v[2] + b.z);
                o.s[3] = f2bf(v[3] + b.w);
                ushort* dst = left ? (xlb + (size_t)grow * HC + gcol)
                                   : (xrb + (size_t)grow * HC + gcol - HC);
                *(uint2*)dst = o.u;
            }
        }
    }
}

// ---------------------------------------------------------------------------
// node_all v7: v4 skeleton (one 192-thread block / 3 waves per node; wave k =
// hop k; 150K waves for TLP latency hiding) + v6's packed-f32 inner math
// (f32x2 pk_add/pk_max/pk_fma, lrelu as max(v,0.2v), 32-bit gather offsets).
// Reduction order (correct, v4): xor-32 half-merge -> per-head *inv ->
// xor-8/16 head mean. Hop results combined through LDS; one 256 B store.
// ---------------------------------------------------------------------------
__global__ __launch_bounds__(192) void node_all(
    const ushort* __restrict__ xlb, const ushort* __restrict__ xrb,
    const int* __restrict__ cnt, const int* __restrict__ bucket,
    const float* __restrict__ att, const float* __restrict__ gw,
    const float* __restrict__ bias, float* __restrict__ out)
{
    __shared__ float lds[HOPS][CDIM];
    const int n    = blockIdx.x;
    const int k    = threadIdx.x >> 6;   // hop
    const int lane = threadIdx.x & 63;
    const int half = lane >> 5;          // which edge of the pair
    const int sub  = lane & 31;          // channel group: ch = sub*8 .. sub*8+7
    const unsigned laneoff = (unsigned)sub * 8;

    const int deg = min(cnt[k * N_NODES + n], CAP);
    const int* bk = bucket + ((size_t)k * N_NODES + n) * CAP;

    // xr channels for this lane (bf16 -> f32x2 pairs)
    uint4 rq = *(const uint4*)(xrb + (size_t)n * HC + laneoff);
    f32x2 rr[4] = { bf2x(rq.x), bf2x(rq.y), bf2x(rq.z), bf2x(rq.w) };

    const float4 a0 = ((const float4*)(att + (size_t)k * HC))[sub * 2 + 0];
    const float4 a1 = ((const float4*)(att + (size_t)k * HC))[sub * 2 + 1];
    f32x2 w2[4] = { {a0.x, a0.y}, {a0.z, a0.w}, {a1.x, a1.y}, {a1.z, a1.w} };

    float denom = 0.f;
    f32x2 acc2[4] = { {0.f,0.f}, {0.f,0.f}, {0.f,0.f}, {0.f,0.f} };

    if (deg > 0) {
        const int degm1 = deg - 1;
        int myS = (lane < deg) ? bk[lane] : 0;
        const int npair = (deg + 1) >> 1;

        int s0 = __shfl(myS, min(half, degm1));
        uint4 q = *(const uint4*)(xlb + (unsigned)s0 * HC + laneoff);

        for (int j = 0; j < npair; j++) {
            int sn = __shfl(myS, min(2 * (j + 1) + half, degm1));
            uint4 qn = *(const uint4*)(xlb + (unsigned)sn * HC + laneoff);

            f32x2 f0 = bf2x(q.x), f1 = bf2x(q.y);
            f32x2 f2 = bf2x(q.z), f3 = bf2x(q.w);

            f32x2 pp = w2[0] * lrelu2(f0 + rr[0]);
            pp = __builtin_elementwise_fma(w2[1], lrelu2(f1 + rr[1]), pp);
            pp = __builtin_elementwise_fma(w2[2], lrelu2(f2 + rr[2]), pp);
            pp = __builtin_elementwise_fma(w2[3], lrelu2(f3 + rr[3]), pp);
            float p = pp.x + pp.y;

            // per-head reduce: head = 8 consecutive lanes (within half)
            p += __shfl_xor(p, 1);
            p += __shfl_xor(p, 2);
            p += __shfl_xor(p, 4);

            bool valid = (2 * j + half) < deg;
            float ex = valid ? __expf(p) : 0.f;
            denom += ex;
            f32x2 ex2 = { ex, ex };
            acc2[0] = __builtin_elementwise_fma(ex2, f0, acc2[0]);
            acc2[1] = __builtin_elementwise_fma(ex2, f1, acc2[1]);
            acc2[2] = __builtin_elementwise_fma(ex2, f2, acc2[2]);
            acc2[3] = __builtin_elementwise_fma(ex2, f3, acc2[3]);
            q = qn;
        }
    }

    // merge halves (xor-32): denom & acc are per-head after this.
    denom += __shfl_xor(denom, 32);
    const float inv = (denom > 0.f) ? 1.f / denom : 0.f;
    const float g   = gw[n * HOPS + k];
    const float* bb = bias + (size_t)k * CDIM + (size_t)(sub & 7) * 8;

    // per-head normalize FIRST (each lane still carries its own head),
    // THEN head mean across lanes {sub&7, +8, +16, +24} (xor-8, xor-16).
    #pragma unroll
    for (int i = 0; i < 4; i++) {
        acc2[i].x += __shfl_xor(acc2[i].x, 32);
        acc2[i].y += __shfl_xor(acc2[i].y, 32);
        acc2[i].x *= inv;
        acc2[i].y *= inv;
        acc2[i].x += __shfl_xor(acc2[i].x, 8);
        acc2[i].y += __shfl_xor(acc2[i].y, 8);
        acc2[i].x += __shfl_xor(acc2[i].x, 16);
        acc2[i].y += __shfl_xor(acc2[i].y, 16);
        if (lane < 8) {
            lds[k][lane * 8 + 2 * i]     = g * (acc2[i].x * 0.25f + bb[2 * i]);
            lds[k][lane * 8 + 2 * i + 1] = g * (acc2[i].y * 0.25f + bb[2 * i + 1]);
        }
    }
    __syncthreads();

    if (threadIdx.x < CDIM)
        out[(size_t)n * CDIM + threadIdx.x] =
            lds[0][threadIdx.x] + lds[1][threadIdx.x] + lds[2][threadIdx.x];
}

// ---------------------------------------------------------------------------
extern "C" void kernel_launch(void* const* d_in, const int* in_sizes, int n_in,
                              void* d_out, int out_size, void* d_ws, size_t ws_size,
                              hipStream_t stream)
{
    const float* x      = (const float*)d_in[0];
    const int*   ei0    = (const int*)d_in[1];
    const int*   ei1    = (const int*)d_in[2];
    const int*   ei2    = (const int*)d_in[3];
    const float* W_l    = (const float*)d_in[4];
    const float* b_l    = (const float*)d_in[5];
    const float* W_r    = (const float*)d_in[6];
    const float* b_r    = (const float*)d_in[7];
    const float* att    = (const float*)d_in[8];   // [3,4,64]
    const float* bias   = (const float*)d_in[9];   // [3,64]
    const float* W_gate = (const float*)d_in[10];  // [256,3]
    const float* b_gate = (const float*)d_in[11];  // [3]

    const size_t NHC = (size_t)N_NODES * HC;       // 12,800,000
    float* ws      = (float*)d_ws;
    float* gwbuf   = ws;                           // 150,000
    int*   cnt     = (int*)(gwbuf + HOPS * N_NODES);         // 150,000
    int*   bucket  = cnt + HOPS * N_NODES;         // 3*N*CAP = 6,000,000
    ushort* xlb    = (ushort*)(bucket + (size_t)HOPS * N_NODES * CAP); // NHC bf16
    ushort* xrb    = xlb + NHC;                    // NHC bf16
    ushort* Xb     = xrb + NHC;                    // NHC bf16
    ushort* WT     = Xb + NHC;                     // 131,072 bf16

    hipMemsetAsync(cnt, 0, (size_t)HOPS * N_NODES * sizeof(int), stream);

    // fused gate+pack_x | pack_w | bucket scatter
    prep<<<NB_GATE + NB_PACKW + NB_SCAT, 256, 0, stream>>>(
        x, W_gate, b_gate, gwbuf, Xb, W_l, W_r, WT,
        ei0, ei1, ei2, cnt, bucket);

    // bf16 MFMA GEMM -> xlb | xrb (both bf16)
    dim3 ggrid(GEMM_BX, 4);
    gemm_mfma<<<ggrid, 256, 0, stream>>>(Xb, WT, b_l, b_r, xlb, xrb, N_NODES);

    // fused logits + softmax + aggregate + head-mean + gate combine
    node_all<<<N_NODES, 192, 0, stream>>>(
        xlb, xrb, cnt, bucket, att, gwbuf, bias, (float*)d_out);
}